// Round 6
// baseline (381.207 us; speedup 1.0000x reference)
//
#include <hip/hip_runtime.h>

#define T_TOK 2048
#define DIM   2048
#define NEXP  8
#define FF    768
#define NGRP  16   // (expert, slot)
#define BK    32

typedef unsigned short u16;
typedef unsigned int   u32;
typedef __bf16 bf16x8 __attribute__((ext_vector_type(8)));
typedef float  f32x4  __attribute__((ext_vector_type(4)));
typedef u16    u16x4  __attribute__((ext_vector_type(4)));
typedef u16    u16x8  __attribute__((ext_vector_type(8)));

#define AS1 __attribute__((address_space(1)))
#define AS3 __attribute__((address_space(3)))

__device__ __forceinline__ u16 f2bf(float f) {
    union { u32 i; float f; } v; v.f = f;
    u32 r = v.i + 0x7FFF + ((v.i >> 16) & 1);   // round-to-nearest-even
    return (u16)(r >> 16);
}
__device__ __forceinline__ float bf2f(u16 u) {
    union { u32 i; float f; } v; v.i = ((u32)u) << 16; return v.f;
}

// async global->LDS, 16B per lane; LDS dest = wave-uniform base + lane*16
__device__ __forceinline__ void gload16(const u16* g, u16* l) {
    __builtin_amdgcn_global_load_lds((const AS1 u32*)g, (AS3 u32*)l, 16, 0, 0);
}

// ---- fp32 -> bf16 bulk convert, 3 weight tensors ----
// Compile-time trip count (4), unrolled: 8 outstanding 16B loads per thread.
__global__ void cvt3_kernel(const float* __restrict__ s0, u16* __restrict__ d0,
                            const float* __restrict__ s1, u16* __restrict__ d1,
                            const float* __restrict__ s2, u16* __restrict__ d2) {
    const float* __restrict__ s; u16* __restrict__ d;
    switch (blockIdx.y) {
        case 0: s = s0; d = d0; break;
        case 1: s = s1; d = d1; break;
        default: s = s2; d = d2; break;
    }
    const size_t st = 1536u * 256u;                 // threads per y-slice
    size_t t = (size_t)blockIdx.x * 256 + threadIdx.x;
    // n8 = NEXP*FF*DIM/8 = 1,572,864 = 4 * st exactly
#pragma unroll
    for (int it = 0; it < 4; it++) {
        size_t i = t + (size_t)it * st;             // u16x8-group index
        f32x4 a = ((const f32x4*)s)[i * 2];
        f32x4 b = ((const f32x4*)s)[i * 2 + 1];
        u16x8 o;
#pragma unroll
        for (int j = 0; j < 4; j++) { o[j] = f2bf(a[j]); o[4 + j] = f2bf(b[j]); }
        ((u16x8*)d)[i] = o;
    }
}

// ------- Router: scores, top-2, softmax, counts; also emits xb = bf16(x) -------
__global__ void router_kernel(const float* __restrict__ x, const float* __restrict__ wr,
                              int* cnt, int* rt_e, float* rt_p, u16* __restrict__ xb) {
    int wave = threadIdx.x >> 6, lane = threadIdx.x & 63;
    int t = blockIdx.x * 4 + wave;
    float xv[32];
#pragma unroll
    for (int i = 0; i < 32; i++) xv[i] = x[(size_t)t * DIM + i * 64 + lane];
#pragma unroll
    for (int i = 0; i < 32; i++) xb[(size_t)t * DIM + i * 64 + lane] = f2bf(xv[i]);
    float s[NEXP];
#pragma unroll
    for (int e = 0; e < NEXP; e++) {
        float acc = 0.f;
#pragma unroll
        for (int i = 0; i < 32; i++) acc += xv[i] * wr[(size_t)e * DIM + i * 64 + lane];
        for (int off = 32; off; off >>= 1) acc += __shfl_xor(acc, off);
        s[e] = acc;
    }
    if (lane == 0) {
        int bi = 0; float bv = s[0];
        for (int e = 1; e < NEXP; e++) if (s[e] > bv) { bv = s[e]; bi = e; }
        float sv = -1e30f; int si = 0;
        for (int e = 0; e < NEXP; e++) { if (e == bi) continue; if (s[e] > sv) { sv = s[e]; si = e; } }
        float p0 = 1.f / (1.f + __expf(sv - bv));
        float p1 = 1.f - p0;
        rt_e[t * 2 + 0] = bi; rt_e[t * 2 + 1] = si;
        rt_p[t * 2 + 0] = p0; rt_p[t * 2 + 1] = p1;
        atomicAdd(&cnt[bi * 2 + 0], 1);
        atomicAdd(&cnt[si * 2 + 1], 1);
    }
}

// ---- Fused scan + assign: one block. Wave 0 scans; all waves then assign rows. ----
__global__ void scanassign_kernel(const int* cnt, const int* rt_e, const float* rt_p,
                                  int* base_g, int* tile_g, int* tile_m0, int* ntiles,
                                  int* rowtok, float* rowprob) {
    __shared__ int s_base[NGRP];
    __shared__ int s_pos[NGRP];
    int tid = threadIdx.x;
    if (tid < NGRP) s_pos[tid] = 0;
    if (tid < 64) {
        int lane = tid;
        int c = (lane < NGRP) ? cnt[lane] : 0;
        int nt_g = (c + 127) >> 7;
        int pre = 0, tpre = 0;
        for (int i = 0; i < NGRP; i++) {
            int ci = __shfl(c, i), ti = __shfl(nt_g, i);
            if (i < lane) { pre += ci; tpre += ti; }
        }
        if (lane < NGRP) {
            s_base[lane] = pre; base_g[lane] = pre;
            for (int j = 0; j < nt_g; j++) { tile_g[tpre + j] = lane; tile_m0[tpre + j] = j * 128; }
            if (lane == NGRP - 1) *ntiles = tpre + nt_g;
        }
    }
    __syncthreads();
    for (int t = tid; t < T_TOK; t += 256) {
#pragma unroll
        for (int k = 0; k < 2; k++) {
            int g = rt_e[t * 2 + k] * 2 + k;
            int pos = atomicAdd(&s_pos[g], 1);
            int row = s_base[g] + pos;
            rowtok[row] = t;
            rowprob[row] = rt_p[t * 2 + k];
        }
    }
}

// ---- Gate/Up GEMM + SiLU: 128 rows x 32 f (64 out-cols: gate|up 16-col frags) ----
// High-parallelism geometry: grid 48x24 = 816 live-ish blocks, LDS 25.5 KB ->
// up to 6 blocks/CU. Per-wave 64x32 (acc 4x2), BK=32, dbuf, counted vmcnt(3).
// Swizzle invariant (BK=32: 4 chunks of 16B per 64B row):
//   LDS[row][c] = global chunk c ^ ((row>>1)&3), both staging-source and read side.
__launch_bounds__(256)
__global__ void gateup_kernel(const u16* __restrict__ xb, const u16* __restrict__ wgb,
                              const u16* __restrict__ wub,
                              const int* cnt, const int* base, const int* tile_g,
                              const int* tile_m0, const int* ntiles,
                              const int* rowtok, const float* rowprob,
                              u16* __restrict__ hidden) {
    int tile = blockIdx.x;
    if (tile >= *ntiles) return;
    int g = tile_g[tile], m0 = tile_m0[tile];
    int e = g >> 1;
    int f0 = blockIdx.y * 32;
    int cg = cnt[g], bg_ = base[g];

    __shared__ u16 As[2][128 * BK];   // 2 x 8 KB
    __shared__ u16 Bs[2][64 * BK];    // 2 x 4 KB
    __shared__ int   tks[128];
    __shared__ float ps[128];

    int tid = threadIdx.x;
    if (tid < 128) {
        int valid = (m0 + tid) < cg;
        tks[tid] = valid ? rowtok[bg_ + m0 + tid] : 0;
        ps[tid]  = valid ? rowprob[bg_ + m0 + tid] : 0.f;
    }
    __syncthreads();

    int wave = tid >> 6, lane = tid & 63;
    int quad = lane >> 4, l16 = lane & 15;
    int wr = wave >> 1, wc = wave & 1;

    // staging: gload16 group = 16 rows x 4 chunks of 16B (row = 64B)
    int r4 = lane >> 2;                                  // 0..15 row in group
    int cw = ((lane & 3) ^ ((r4 >> 1) & 3)) * 8;         // inverse-swizzled src chunk (elems)

    // A: wave stages rows wave*32 + {0,16} + r4
    const u16* gA0 = xb + (size_t)tks[wave * 32 + r4] * DIM + cw;
    const u16* gA1 = xb + (size_t)tks[wave * 32 + 16 + r4] * DIM + cw;
    int lA0 = (wave * 32) * BK, lA1 = (wave * 32 + 16) * BK;
    // B LDS row n in [0,64): type=(n>>4)&1 (0=gate,1=up), f = f0 + (n>>5)*16 + (n&15)
    // wave stages rows wave*16 + r4
    const u16* bsrc = (wave & 1) ? wub : wgb;
    const u16* gB = bsrc + ((size_t)e * FF + f0 + (wave >> 1) * 16 + r4) * DIM + cw;
    int lB = (wave * 16) * BK;

    // ds-read offsets (loop-invariant): chunk = quad ^ ((l16>>1)&3)
    int swz = (quad ^ ((l16 >> 1) & 3)) * 8;
    int aoff[4], boff[2];
#pragma unroll
    for (int mi = 0; mi < 4; mi++) aoff[mi] = (wr * 64 + mi * 16 + l16) * BK + swz;
#pragma unroll
    for (int ni = 0; ni < 2; ni++) boff[ni] = (wc * 32 + ni * 16 + l16) * BK + swz;

    f32x4 acc[4][2] = {};

    // prologue: stage buffer 0 (3 loads/lane, left in flight)
    gload16(gA0, &As[0][0] + lA0);
    gload16(gA1, &As[0][0] + lA1);
    gload16(gB,  &Bs[0][0] + lB);

    for (int kt = 0; kt < DIM / BK; kt++) {
        int cur = kt & 1;
        int kk = (kt + 1) * BK;
        if (kk < DIM) {
            gload16(gA0 + kk, &As[cur ^ 1][0] + lA0);
            gload16(gA1 + kk, &As[cur ^ 1][0] + lA1);
            gload16(gB + kk,  &Bs[cur ^ 1][0] + lB);
            __builtin_amdgcn_sched_barrier(0);
            asm volatile("s_waitcnt vmcnt(3)" ::: "memory");
        } else {
            __builtin_amdgcn_sched_barrier(0);
            asm volatile("s_waitcnt vmcnt(0)" ::: "memory");
        }
        __builtin_amdgcn_s_barrier();             // buf[cur] visible to all waves
        __builtin_amdgcn_sched_barrier(0);
        bf16x8 a[4], b[2];
#pragma unroll
        for (int mi = 0; mi < 4; mi++) a[mi] = *(const bf16x8*)&As[cur][aoff[mi]];
#pragma unroll
        for (int ni = 0; ni < 2; ni++) b[ni] = *(const bf16x8*)&Bs[cur][boff[ni]];
#pragma unroll
        for (int mi = 0; mi < 4; mi++)
#pragma unroll
            for (int ni = 0; ni < 2; ni++)
                acc[mi][ni] = __builtin_amdgcn_mfma_f32_16x16x32_bf16(a[mi], b[ni], acc[mi][ni], 0, 0, 0);
        __builtin_amdgcn_sched_barrier(0);
        asm volatile("s_waitcnt lgkmcnt(0)" ::: "memory");   // my reads of buf[cur] done
        __builtin_amdgcn_s_barrier();             // safe to overwrite buf[cur]
    }

    // epilogue: gate = acc[mi][0], up = acc[mi][1]; f = f0 + wc*16 + l16
    int f = f0 + wc * 16 + l16;
#pragma unroll
    for (int mi = 0; mi < 4; mi++) {
#pragma unroll
        for (int r = 0; r < 4; r++) {
            int m = wr * 64 + mi * 16 + quad * 4 + r;
            if (m0 + m < cg) {
                float gv = acc[mi][0][r], uv = acc[mi][1][r];
                float h = (gv / (1.f + __expf(-gv))) * uv * ps[m];
                hidden[(size_t)(bg_ + m0 + m) * FF + f] = f2bf(h);
            }
        }
    }
}

// ---- Down GEMM: 128 rows x 64 d, per-wave 64x32 (acc 4x2), BK=32, dbuf ----
// grid 48x32 = up to 1088 live blocks; same counted-vmcnt pipeline + swizzle.
__launch_bounds__(256)
__global__ void down_kernel(const u16* __restrict__ hid, const u16* __restrict__ wdb,
                            const int* cnt, const int* base, const int* tile_g,
                            const int* tile_m0, const int* ntiles, const int* rowtok,
                            u16* __restrict__ out0, u16* __restrict__ out1) {
    int tile = blockIdx.x;
    if (tile >= *ntiles) return;
    int g = tile_g[tile], m0 = tile_m0[tile];
    int e = g >> 1, slot = g & 1;
    int d0 = blockIdx.y * 64;
    int cg = cnt[g], bg_ = base[g];

    __shared__ u16 As[2][128 * BK];   // 2 x 8 KB
    __shared__ u16 Bs[2][64 * BK];    // 2 x 4 KB
    __shared__ int tks[128];

    int tid = threadIdx.x;
    if (tid < 128) tks[tid] = ((m0 + tid) < cg) ? rowtok[bg_ + m0 + tid] : 0;
    __syncthreads();

    int wave = tid >> 6, lane = tid & 63;
    int quad = lane >> 4, l16 = lane & 15;
    int wr = wave >> 1, wc = wave & 1;

    int r4 = lane >> 2;
    int cw = ((lane & 3) ^ ((r4 >> 1) & 3)) * 8;

    const u16* gA0 = hid + (size_t)(bg_ + m0 + wave * 32 + r4) * FF + cw;
    const u16* gA1 = hid + (size_t)(bg_ + m0 + wave * 32 + 16 + r4) * FF + cw;
    int lA0 = (wave * 32) * BK, lA1 = (wave * 32 + 16) * BK;
    // B LDS row n in [0,64): d = d0 + n; wave stages rows wave*16 + r4
    const u16* gB = wdb + ((size_t)e * DIM + d0 + wave * 16 + r4) * FF + cw;
    int lB = (wave * 16) * BK;

    int swz = (quad ^ ((l16 >> 1) & 3)) * 8;
    int aoff[4], boff[2];
#pragma unroll
    for (int mi = 0; mi < 4; mi++) aoff[mi] = (wr * 64 + mi * 16 + l16) * BK + swz;
#pragma unroll
    for (int ni = 0; ni < 2; ni++) boff[ni] = (wc * 32 + ni * 16 + l16) * BK + swz;

    f32x4 acc[4][2] = {};

    gload16(gA0, &As[0][0] + lA0);
    gload16(gA1, &As[0][0] + lA1);
    gload16(gB,  &Bs[0][0] + lB);

    for (int kt = 0; kt < FF / BK; kt++) {
        int cur = kt & 1;
        int kk = (kt + 1) * BK;
        if (kk < FF) {
            gload16(gA0 + kk, &As[cur ^ 1][0] + lA0);
            gload16(gA1 + kk, &As[cur ^ 1][0] + lA1);
            gload16(gB + kk,  &Bs[cur ^ 1][0] + lB);
            __builtin_amdgcn_sched_barrier(0);
            asm volatile("s_waitcnt vmcnt(3)" ::: "memory");
        } else {
            __builtin_amdgcn_sched_barrier(0);
            asm volatile("s_waitcnt vmcnt(0)" ::: "memory");
        }
        __builtin_amdgcn_s_barrier();
        __builtin_amdgcn_sched_barrier(0);
        bf16x8 a[4], b[2];
#pragma unroll
        for (int mi = 0; mi < 4; mi++) a[mi] = *(const bf16x8*)&As[cur][aoff[mi]];
#pragma unroll
        for (int ni = 0; ni < 2; ni++) b[ni] = *(const bf16x8*)&Bs[cur][boff[ni]];
#pragma unroll
        for (int mi = 0; mi < 4; mi++)
#pragma unroll
            for (int ni = 0; ni < 2; ni++)
                acc[mi][ni] = __builtin_amdgcn_mfma_f32_16x16x32_bf16(a[mi], b[ni], acc[mi][ni], 0, 0, 0);
        __builtin_amdgcn_sched_barrier(0);
        asm volatile("s_waitcnt lgkmcnt(0)" ::: "memory");
        __builtin_amdgcn_s_barrier();
    }

    u16* outp = slot ? out1 : out0;
#pragma unroll
    for (int mi = 0; mi < 4; mi++) {
#pragma unroll
        for (int ni = 0; ni < 2; ni++) {
            int d = d0 + wc * 32 + ni * 16 + l16;
#pragma unroll
            for (int r = 0; r < 4; r++) {
                int m = wr * 64 + mi * 16 + quad * 4 + r;
                if (m0 + m < cg) {
                    outp[(size_t)tks[m] * DIM + d] = f2bf(acc[mi][ni][r]);
                }
            }
        }
    }
}

// ---------------- Combine: out = f32(o0) + f32(o1) ----------------
__global__ void combine_kernel(const u16* __restrict__ o0, const u16* __restrict__ o1,
                               float* __restrict__ out) {
    int i = blockIdx.x * blockDim.x + threadIdx.x;
    u16x8 a = *(const u16x8*)(o0 + (size_t)i * 8);
    u16x8 b = *(const u16x8*)(o1 + (size_t)i * 8);
    f32x4 r0, r1;
#pragma unroll
    for (int j = 0; j < 4; j++) {
        r0[j] = bf2f(a[j]) + bf2f(b[j]);
        r1[j] = bf2f(a[4 + j]) + bf2f(b[4 + j]);
    }
    *(f32x4*)(out + (size_t)i * 8) = r0;
    *(f32x4*)(out + (size_t)i * 8 + 4) = r1;
}

extern "C" void kernel_launch(void* const* d_in, const int* in_sizes, int n_in,
                              void* d_out, int out_size, void* d_ws, size_t ws_size,
                              hipStream_t stream) {
    const float* x  = (const float*)d_in[0];
    const float* wr = (const float*)d_in[1];
    const float* wg = (const float*)d_in[2];
    const float* wu = (const float*)d_in[3];
    const float* wd = (const float*)d_in[4];
    float* out = (float*)d_out;

    char* W = (char*)d_ws;
    int*   cnt     = (int*)(W + 0);
    int*   base    = (int*)(W + 128);
    int*   ntiles  = (int*)(W + 192);
    int*   tile_g  = (int*)(W + 256);           // <=48
    int*   tile_m0 = (int*)(W + 512);           // <=48
    int*   rt_e    = (int*)(W + 1024);          // 4096 ints
    float* rt_p    = (float*)(W + 20480);
    int*   rowtok  = (int*)(W + 40960);
    float* rowprob = (float*)(W + 61440);
    u16*   hidden  = (u16*)(W + 81920);         // (4096+128) x 768 bf16 ~ 6.49 MB
    u16*   xb      = (u16*)(W + ((size_t)8  << 20));   // 8.39 MB
    u16*   wgb     = (u16*)(W + ((size_t)17 << 20));   // 25.2 MB (dead after gateup)
    u16*   wub     = (u16*)(W + ((size_t)43 << 20));   // 25.2 MB (dead after gateup)
    u16*   wdb     = (u16*)(W + ((size_t)69 << 20));   // 25.2 MB  (end ~94.4 MB)
    // out0/out1 overlap the wgb region (only written by down, after gateup finished)
    u16*   out0    = (u16*)(W + ((size_t)17 << 20));   // 8.39 MB
    u16*   out1    = (u16*)(W + ((size_t)26 << 20));   // 8.39 MB

    hipMemsetAsync(W, 0, 256, stream);   // cnt, base, ntiles

    cvt3_kernel<<<dim3(1536, 3), 256, 0, stream>>>(wg, wgb, wu, wub, wd, wdb);

    router_kernel<<<T_TOK / 4, 256, 0, stream>>>(x, wr, cnt, rt_e, rt_p, xb);
    scanassign_kernel<<<1, 256, 0, stream>>>(cnt, rt_e, rt_p, base, tile_g, tile_m0,
                                             ntiles, rowtok, rowprob);

    gateup_kernel<<<dim3(48, 24), 256, 0, stream>>>(xb, wgb, wub, cnt, base, tile_g, tile_m0,
                                                    ntiles, rowtok, rowprob, hidden);
    down_kernel<<<dim3(48, 32), 256, 0, stream>>>(hidden, wdb, cnt, base, tile_g, tile_m0,
                                                  ntiles, rowtok, out0, out1);
    combine_kernel<<<T_TOK * DIM / (256 * 8), 256, 0, stream>>>(out0, out1, out);
}

// Round 7
// 378.527 us; speedup vs baseline: 1.0071x; 1.0071x over previous
//
#include <hip/hip_runtime.h>

#define T_TOK 2048
#define DIM   2048
#define NEXP  8
#define FF    768
#define NGRP  16   // (expert, slot)
#define BK    64

typedef unsigned short u16;
typedef unsigned int   u32;
typedef __bf16 bf16x8 __attribute__((ext_vector_type(8)));
typedef float  f32x4  __attribute__((ext_vector_type(4)));
typedef u16    u16x4  __attribute__((ext_vector_type(4)));
typedef u16    u16x8  __attribute__((ext_vector_type(8)));

#define AS1 __attribute__((address_space(1)))
#define AS3 __attribute__((address_space(3)))

__device__ __forceinline__ u16 f2bf(float f) {
    union { u32 i; float f; } v; v.f = f;
    u32 r = v.i + 0x7FFF + ((v.i >> 16) & 1);   // round-to-nearest-even
    return (u16)(r >> 16);
}
__device__ __forceinline__ float bf2f(u16 u) {
    union { u32 i; float f; } v; v.i = ((u32)u) << 16; return v.f;
}

// async global->LDS, 16B per lane; LDS dest = wave-uniform base + lane*16
__device__ __forceinline__ void gload16(const u16* g, u16* l) {
    __builtin_amdgcn_global_load_lds((const AS1 u32*)g, (AS3 u32*)l, 16, 0, 0);
}

// ---- fp32 -> bf16 bulk convert, 3 weight tensors ----
// Compile-time trip count (4), unrolled: 8 outstanding 16B loads per thread.
__global__ void cvt3_kernel(const float* __restrict__ s0, u16* __restrict__ d0,
                            const float* __restrict__ s1, u16* __restrict__ d1,
                            const float* __restrict__ s2, u16* __restrict__ d2) {
    const float* __restrict__ s; u16* __restrict__ d;
    switch (blockIdx.y) {
        case 0: s = s0; d = d0; break;
        case 1: s = s1; d = d1; break;
        default: s = s2; d = d2; break;
    }
    const size_t st = 1536u * 256u;                 // threads per y-slice
    size_t t = (size_t)blockIdx.x * 256 + threadIdx.x;
    // n8 = NEXP*FF*DIM/8 = 1,572,864 = 4 * st exactly
#pragma unroll
    for (int it = 0; it < 4; it++) {
        size_t i = t + (size_t)it * st;             // u16x8-group index
        f32x4 a = ((const f32x4*)s)[i * 2];
        f32x4 b = ((const f32x4*)s)[i * 2 + 1];
        u16x8 o;
#pragma unroll
        for (int j = 0; j < 4; j++) { o[j] = f2bf(a[j]); o[4 + j] = f2bf(b[j]); }
        ((u16x8*)d)[i] = o;
    }
}

// ------- Router: scores, top-2, softmax, counts; also emits xb = bf16(x) -------
__global__ void router_kernel(const float* __restrict__ x, const float* __restrict__ wr,
                              int* cnt, int* rt_e, float* rt_p, u16* __restrict__ xb) {
    int wave = threadIdx.x >> 6, lane = threadIdx.x & 63;
    int t = blockIdx.x * 4 + wave;
    float xv[32];
#pragma unroll
    for (int i = 0; i < 32; i++) xv[i] = x[(size_t)t * DIM + i * 64 + lane];
#pragma unroll
    for (int i = 0; i < 32; i++) xb[(size_t)t * DIM + i * 64 + lane] = f2bf(xv[i]);
    float s[NEXP];
#pragma unroll
    for (int e = 0; e < NEXP; e++) {
        float acc = 0.f;
#pragma unroll
        for (int i = 0; i < 32; i++) acc += xv[i] * wr[(size_t)e * DIM + i * 64 + lane];
        for (int off = 32; off; off >>= 1) acc += __shfl_xor(acc, off);
        s[e] = acc;
    }
    if (lane == 0) {
        int bi = 0; float bv = s[0];
        for (int e = 1; e < NEXP; e++) if (s[e] > bv) { bv = s[e]; bi = e; }
        float sv = -1e30f; int si = 0;
        for (int e = 0; e < NEXP; e++) { if (e == bi) continue; if (s[e] > sv) { sv = s[e]; si = e; } }
        float p0 = 1.f / (1.f + __expf(sv - bv));
        float p1 = 1.f - p0;
        rt_e[t * 2 + 0] = bi; rt_e[t * 2 + 1] = si;
        rt_p[t * 2 + 0] = p0; rt_p[t * 2 + 1] = p1;
        atomicAdd(&cnt[bi * 2 + 0], 1);
        atomicAdd(&cnt[si * 2 + 1], 1);
    }
}

// ---- Fused scan + assign: one block. Wave 0 scans; all waves then assign rows. ----
__global__ void scanassign_kernel(const int* cnt, const int* rt_e, const float* rt_p,
                                  int* base_g, int* tile_g, int* tile_m0, int* ntiles,
                                  int* rowtok, float* rowprob) {
    __shared__ int s_base[NGRP];
    __shared__ int s_pos[NGRP];
    int tid = threadIdx.x;
    if (tid < NGRP) s_pos[tid] = 0;
    if (tid < 64) {
        int lane = tid;
        int c = (lane < NGRP) ? cnt[lane] : 0;
        int nt_g = (c + 127) >> 7;
        int pre = 0, tpre = 0;
        for (int i = 0; i < NGRP; i++) {
            int ci = __shfl(c, i), ti = __shfl(nt_g, i);
            if (i < lane) { pre += ci; tpre += ti; }
        }
        if (lane < NGRP) {
            s_base[lane] = pre; base_g[lane] = pre;
            for (int j = 0; j < nt_g; j++) { tile_g[tpre + j] = lane; tile_m0[tpre + j] = j * 128; }
            if (lane == NGRP - 1) *ntiles = tpre + nt_g;
        }
    }
    __syncthreads();
    for (int t = tid; t < T_TOK; t += 256) {
#pragma unroll
        for (int k = 0; k < 2; k++) {
            int g = rt_e[t * 2 + k] * 2 + k;
            int pos = atomicAdd(&s_pos[g], 1);
            int row = s_base[g] + pos;
            rowtok[row] = t;
            rowprob[row] = rt_p[t * 2 + k];
        }
    }
}

// ---- Gate/Up GEMM + SiLU: 128 rows x 32 f (64 out-cols: gate|up 16-col frags) ----
// r1 geometry (best measured: 816 live blocks) + 3-buffer, 2-AHEAD pipeline:
// stage kt+2, wait vmcnt(12) (= 2 stages x 6 loads in flight), barrier, compute.
// A 1-deep prefetch cannot hide latency longer than one iteration; 2-deep can.
// LDS 74 KB -> 2 blocks/CU.
__launch_bounds__(256)
__global__ void gateup_kernel(const u16* __restrict__ xb, const u16* __restrict__ wgb,
                              const u16* __restrict__ wub,
                              const int* cnt, const int* base, const int* tile_g,
                              const int* tile_m0, const int* ntiles,
                              const int* rowtok, const float* rowprob,
                              u16* __restrict__ hidden) {
    int tile = blockIdx.x;
    if (tile >= *ntiles) return;
    int g = tile_g[tile], m0 = tile_m0[tile];
    int e = g >> 1;
    int f0 = blockIdx.y * 32;
    int cg = cnt[g], bg_ = base[g];

    __shared__ u16 As[3][128 * BK];   // 3 x 16 KB
    __shared__ u16 Bs[3][64 * BK];    // 3 x 8 KB
    __shared__ int   tks[128];
    __shared__ float ps[128];

    int tid = threadIdx.x;
    if (tid < 128) {
        int valid = (m0 + tid) < cg;
        tks[tid] = valid ? rowtok[bg_ + m0 + tid] : 0;
        ps[tid]  = valid ? rowprob[bg_ + m0 + tid] : 0.f;
    }
    __syncthreads();

    int wave = tid >> 6, lane = tid & 63;
    int quad = lane >> 4, l16 = lane & 15;
    int wr = wave >> 1, wc = wave & 1;

    // staging: 8 rows x 8 chunks of 16B per gload16 group
    int r8  = lane >> 3;                  // row within 8-row group
    int csw = ((lane & 7) ^ r8) * 8;      // inverse-swizzled global chunk (elements)

    // A: wave stages rows [wave*32, +32) in 4 groups of 8
    const u16* gA[4]; int lA[4];
#pragma unroll
    for (int gi = 0; gi < 4; gi++) {
        int row = wave * 32 + gi * 8 + r8;
        gA[gi] = xb + (size_t)tks[row] * DIM + csw;
        lA[gi] = (wave * 32 + gi * 8) * BK;
    }
    // B LDS row n in [0,64): type=(n>>4)&1 (0=gate,1=up), f = f0 + (n>>5)*16 + (n&15)
    // wave stages rows [wave*16, +16) in 2 groups of 8
    const u16* bsrc = (wave & 1) ? wub : wgb;
    const u16* gB[2]; int lB[2];
#pragma unroll
    for (int gi = 0; gi < 2; gi++) {
        int f = f0 + (wave >> 1) * 16 + gi * 8 + r8;
        gB[gi] = bsrc + ((size_t)e * FF + f) * DIM + csw;
        lB[gi] = (wave * 16 + gi * 8) * BK;
    }

    int sw0 = ((0 * 4 + quad) ^ (l16 & 7)) * 8;
    int sw1 = ((1 * 4 + quad) ^ (l16 & 7)) * 8;

    f32x4 acc[4][2] = {};

#define GU_STAGE(kkof, bi) do {                                          \
    _Pragma("unroll")                                                    \
    for (int gi = 0; gi < 4; gi++) gload16(gA[gi] + (kkof), &As[bi][0] + lA[gi]); \
    _Pragma("unroll")                                                    \
    for (int gi = 0; gi < 2; gi++) gload16(gB[gi] + (kkof), &Bs[bi][0] + lB[gi]); \
} while (0)

#define GU_COMPUTE(bi) do {                                              \
    _Pragma("unroll")                                                    \
    for (int ks = 0; ks < 2; ks++) {                                     \
        int sw = ks ? sw1 : sw0;                                         \
        bf16x8 a[4], b[2];                                               \
        _Pragma("unroll")                                                \
        for (int mi = 0; mi < 4; mi++)                                   \
            a[mi] = *(const bf16x8*)&As[bi][(wr * 64 + mi * 16 + l16) * BK + sw]; \
        _Pragma("unroll")                                                \
        for (int ni = 0; ni < 2; ni++)                                   \
            b[ni] = *(const bf16x8*)&Bs[bi][(wc * 32 + ni * 16 + l16) * BK + sw]; \
        _Pragma("unroll")                                                \
        for (int mi = 0; mi < 4; mi++)                                   \
            _Pragma("unroll")                                            \
            for (int ni = 0; ni < 2; ni++)                               \
                acc[mi][ni] = __builtin_amdgcn_mfma_f32_16x16x32_bf16(a[mi], b[ni], acc[mi][ni], 0, 0, 0); \
    }                                                                    \
} while (0)

    // prologue: stage buffers 0 and 1 (12 loads/lane in flight)
    GU_STAGE(0, 0);
    GU_STAGE(BK, 1);

    const int NT = DIM / BK;   // 32
    int cur = 0;
    for (int kt = 0; kt < NT - 2; kt++) {
        int s2 = cur + 2; if (s2 >= 3) s2 -= 3;
        GU_STAGE((kt + 2) * BK, s2);
        __builtin_amdgcn_sched_barrier(0);
        asm volatile("s_waitcnt vmcnt(12)" ::: "memory");   // buf[cur] complete
        __builtin_amdgcn_s_barrier();
        __builtin_amdgcn_sched_barrier(0);
        GU_COMPUTE(cur);
        __builtin_amdgcn_sched_barrier(0);
        asm volatile("s_waitcnt lgkmcnt(0)" ::: "memory");  // my reads of buf[cur] done
        __builtin_amdgcn_s_barrier();                       // safe to overwrite buf[cur]
        cur++; if (cur >= 3) cur = 0;
    }
    // kt = NT-2: one stage (6 loads) still in flight behind it
    __builtin_amdgcn_sched_barrier(0);
    asm volatile("s_waitcnt vmcnt(6)" ::: "memory");
    __builtin_amdgcn_s_barrier();
    __builtin_amdgcn_sched_barrier(0);
    GU_COMPUTE(cur);
    cur++; if (cur >= 3) cur = 0;
    // kt = NT-1
    __builtin_amdgcn_sched_barrier(0);
    asm volatile("s_waitcnt vmcnt(0)" ::: "memory");
    __builtin_amdgcn_s_barrier();
    __builtin_amdgcn_sched_barrier(0);
    GU_COMPUTE(cur);

#undef GU_STAGE
#undef GU_COMPUTE

    // epilogue: gate = acc[mi][0], up = acc[mi][1]; f = f0 + wc*16 + l16
    int f = f0 + wc * 16 + l16;
#pragma unroll
    for (int mi = 0; mi < 4; mi++) {
#pragma unroll
        for (int r = 0; r < 4; r++) {
            int m = wr * 64 + mi * 16 + quad * 4 + r;
            if (m0 + m < cg) {
                float gv = acc[mi][0][r], uv = acc[mi][1][r];
                float h = (gv / (1.f + __expf(-gv))) * uv * ps[m];
                hidden[(size_t)(bg_ + m0 + m) * FF + f] = f2bf(h);
            }
        }
    }
}

// ---- Down GEMM: 128 rows x 64 d, acc 4x2, BK=64, 3-buffer 2-ahead pipeline ----
__launch_bounds__(256)
__global__ void down_kernel(const u16* __restrict__ hid, const u16* __restrict__ wdb,
                            const int* cnt, const int* base, const int* tile_g,
                            const int* tile_m0, const int* ntiles, const int* rowtok,
                            u16* __restrict__ out0, u16* __restrict__ out1) {
    int tile = blockIdx.x;
    if (tile >= *ntiles) return;
    int g = tile_g[tile], m0 = tile_m0[tile];
    int e = g >> 1, slot = g & 1;
    int d0 = blockIdx.y * 64;
    int cg = cnt[g], bg_ = base[g];

    __shared__ u16 As[3][128 * BK];
    __shared__ u16 Bs[3][64 * BK];
    __shared__ int tks[128];

    int tid = threadIdx.x;
    if (tid < 128) tks[tid] = ((m0 + tid) < cg) ? rowtok[bg_ + m0 + tid] : 0;
    __syncthreads();

    int wave = tid >> 6, lane = tid & 63;
    int quad = lane >> 4, l16 = lane & 15;
    int wr = wave >> 1, wc = wave & 1;

    int r8  = lane >> 3;
    int csw = ((lane & 7) ^ r8) * 8;

    const u16* gA[4]; int lA[4];
#pragma unroll
    for (int gi = 0; gi < 4; gi++) {
        int row = wave * 32 + gi * 8 + r8;
        gA[gi] = hid + (size_t)(bg_ + m0 + row) * FF + csw;
        lA[gi] = (wave * 32 + gi * 8) * BK;
    }
    // B LDS row n in [0,64): d = d0 + n; wave stages rows [wave*16,+16) in 2 groups
    const u16* gB[2]; int lB[2];
#pragma unroll
    for (int gi = 0; gi < 2; gi++) {
        int n = wave * 16 + gi * 8 + r8;
        gB[gi] = wdb + ((size_t)e * DIM + d0 + n) * FF + csw;
        lB[gi] = (wave * 16 + gi * 8) * BK;
    }

    int sw0 = ((0 * 4 + quad) ^ (l16 & 7)) * 8;
    int sw1 = ((1 * 4 + quad) ^ (l16 & 7)) * 8;

    f32x4 acc[4][2] = {};

#define DN_STAGE(kkof, bi) do {                                          \
    _Pragma("unroll")                                                    \
    for (int gi = 0; gi < 4; gi++) gload16(gA[gi] + (kkof), &As[bi][0] + lA[gi]); \
    _Pragma("unroll")                                                    \
    for (int gi = 0; gi < 2; gi++) gload16(gB[gi] + (kkof), &Bs[bi][0] + lB[gi]); \
} while (0)

#define DN_COMPUTE(bi) do {                                              \
    _Pragma("unroll")                                                    \
    for (int ks = 0; ks < 2; ks++) {                                     \
        int sw = ks ? sw1 : sw0;                                         \
        bf16x8 a[4], b[2];                                               \
        _Pragma("unroll")                                                \
        for (int mi = 0; mi < 4; mi++)                                   \
            a[mi] = *(const bf16x8*)&As[bi][(wr * 64 + mi * 16 + l16) * BK + sw]; \
        _Pragma("unroll")                                                \
        for (int ni = 0; ni < 2; ni++)                                   \
            b[ni] = *(const bf16x8*)&Bs[bi][(wc * 32 + ni * 16 + l16) * BK + sw]; \
        _Pragma("unroll")                                                \
        for (int mi = 0; mi < 4; mi++)                                   \
            _Pragma("unroll")                                            \
            for (int ni = 0; ni < 2; ni++)                               \
                acc[mi][ni] = __builtin_amdgcn_mfma_f32_16x16x32_bf16(a[mi], b[ni], acc[mi][ni], 0, 0, 0); \
    }                                                                    \
} while (0)

    DN_STAGE(0, 0);
    DN_STAGE(BK, 1);

    const int NT = FF / BK;   // 12
    int cur = 0;
    for (int kt = 0; kt < NT - 2; kt++) {
        int s2 = cur + 2; if (s2 >= 3) s2 -= 3;
        DN_STAGE((kt + 2) * BK, s2);
        __builtin_amdgcn_sched_barrier(0);
        asm volatile("s_waitcnt vmcnt(12)" ::: "memory");
        __builtin_amdgcn_s_barrier();
        __builtin_amdgcn_sched_barrier(0);
        DN_COMPUTE(cur);
        __builtin_amdgcn_sched_barrier(0);
        asm volatile("s_waitcnt lgkmcnt(0)" ::: "memory");
        __builtin_amdgcn_s_barrier();
        cur++; if (cur >= 3) cur = 0;
    }
    __builtin_amdgcn_sched_barrier(0);
    asm volatile("s_waitcnt vmcnt(6)" ::: "memory");
    __builtin_amdgcn_s_barrier();
    __builtin_amdgcn_sched_barrier(0);
    DN_COMPUTE(cur);
    cur++; if (cur >= 3) cur = 0;
    __builtin_amdgcn_sched_barrier(0);
    asm volatile("s_waitcnt vmcnt(0)" ::: "memory");
    __builtin_amdgcn_s_barrier();
    __builtin_amdgcn_sched_barrier(0);
    DN_COMPUTE(cur);

#undef DN_STAGE
#undef DN_COMPUTE

    u16* outp = slot ? out1 : out0;
#pragma unroll
    for (int mi = 0; mi < 4; mi++) {
#pragma unroll
        for (int ni = 0; ni < 2; ni++) {
            int d = d0 + wc * 32 + ni * 16 + l16;
#pragma unroll
            for (int r = 0; r < 4; r++) {
                int m = wr * 64 + mi * 16 + quad * 4 + r;
                if (m0 + m < cg) {
                    outp[(size_t)tks[m] * DIM + d] = f2bf(acc[mi][ni][r]);
                }
            }
        }
    }
}

// ---------------- Combine: out = f32(o0) + f32(o1) ----------------
__global__ void combine_kernel(const u16* __restrict__ o0, const u16* __restrict__ o1,
                               float* __restrict__ out) {
    int i = blockIdx.x * blockDim.x + threadIdx.x;
    u16x8 a = *(const u16x8*)(o0 + (size_t)i * 8);
    u16x8 b = *(const u16x8*)(o1 + (size_t)i * 8);
    f32x4 r0, r1;
#pragma unroll
    for (int j = 0; j < 4; j++) {
        r0[j] = bf2f(a[j]) + bf2f(b[j]);
        r1[j] = bf2f(a[4 + j]) + bf2f(b[4 + j]);
    }
    *(f32x4*)(out + (size_t)i * 8) = r0;
    *(f32x4*)(out + (size_t)i * 8 + 4) = r1;
}

extern "C" void kernel_launch(void* const* d_in, const int* in_sizes, int n_in,
                              void* d_out, int out_size, void* d_ws, size_t ws_size,
                              hipStream_t stream) {
    const float* x  = (const float*)d_in[0];
    const float* wr = (const float*)d_in[1];
    const float* wg = (const float*)d_in[2];
    const float* wu = (const float*)d_in[3];
    const float* wd = (const float*)d_in[4];
    float* out = (float*)d_out;

    char* W = (char*)d_ws;
    int*   cnt     = (int*)(W + 0);
    int*   base    = (int*)(W + 128);
    int*   ntiles  = (int*)(W + 192);
    int*   tile_g  = (int*)(W + 256);           // <=48
    int*   tile_m0 = (int*)(W + 512);           // <=48
    int*   rt_e    = (int*)(W + 1024);          // 4096 ints
    float* rt_p    = (float*)(W + 20480);
    int*   rowtok  = (int*)(W + 40960);
    float* rowprob = (float*)(W + 61440);
    u16*   hidden  = (u16*)(W + 81920);         // (4096+128) x 768 bf16 ~ 6.49 MB
    u16*   xb      = (u16*)(W + ((size_t)8  << 20));   // 8.39 MB
    u16*   wgb     = (u16*)(W + ((size_t)17 << 20));   // 25.2 MB (dead after gateup)
    u16*   wub     = (u16*)(W + ((size_t)43 << 20));   // 25.2 MB (dead after gateup)
    u16*   wdb     = (u16*)(W + ((size_t)69 << 20));   // 25.2 MB  (end ~94.4 MB)
    // out0/out1 overlap the wgb region (only written by down, after gateup finished)
    u16*   out0    = (u16*)(W + ((size_t)17 << 20));   // 8.39 MB
    u16*   out1    = (u16*)(W + ((size_t)26 << 20));   // 8.39 MB

    hipMemsetAsync(W, 0, 256, stream);   // cnt, base, ntiles

    cvt3_kernel<<<dim3(1536, 3), 256, 0, stream>>>(wg, wgb, wu, wub, wd, wdb);

    router_kernel<<<T_TOK / 4, 256, 0, stream>>>(x, wr, cnt, rt_e, rt_p, xb);
    scanassign_kernel<<<1, 256, 0, stream>>>(cnt, rt_e, rt_p, base, tile_g, tile_m0,
                                             ntiles, rowtok, rowprob);

    gateup_kernel<<<dim3(48, 24), 256, 0, stream>>>(xb, wgb, wub, cnt, base, tile_g, tile_m0,
                                                    ntiles, rowtok, rowprob, hidden);
    down_kernel<<<dim3(48, 32), 256, 0, stream>>>(hidden, wdb, cnt, base, tile_g, tile_m0,
                                                  ntiles, rowtok, out0, out1);
    combine_kernel<<<T_TOK * DIM / (256 * 8), 256, 0, stream>>>(out0, out1, out);
}

// Round 8
// 364.226 us; speedup vs baseline: 1.0466x; 1.0393x over previous
//
#include <hip/hip_runtime.h>

#define T_TOK 2048
#define DIM   2048
#define NEXP  8
#define FF    768
#define NGRP  16   // (expert, slot)
#define BK    32

typedef unsigned short u16;
typedef unsigned int   u32;
typedef __bf16 bf16x8 __attribute__((ext_vector_type(8)));
typedef float  f32x4  __attribute__((ext_vector_type(4)));
typedef u16    u16x4  __attribute__((ext_vector_type(4)));
typedef u16    u16x8  __attribute__((ext_vector_type(8)));

#define AS1 __attribute__((address_space(1)))
#define AS3 __attribute__((address_space(3)))

__device__ __forceinline__ u16 f2bf(float f) {
    union { u32 i; float f; } v; v.f = f;
    u32 r = v.i + 0x7FFF + ((v.i >> 16) & 1);   // round-to-nearest-even
    return (u16)(r >> 16);
}
__device__ __forceinline__ float bf2f(u16 u) {
    union { u32 i; float f; } v; v.i = ((u32)u) << 16; return v.f;
}

// async global->LDS, 16B per lane; LDS dest = wave-uniform base + lane*16
__device__ __forceinline__ void gload16(const u16* g, u16* l) {
    __builtin_amdgcn_global_load_lds((const AS1 u32*)g, (AS3 u32*)l, 16, 0, 0);
}

// ---- fp32 -> bf16 bulk convert, 3 weight tensors: one-shot exact grid ----
// Each thread: 2 x f32x4 loads + 1 x u16x8 store, fully coalesced, no loop.
__global__ void cvt3_kernel(const float* __restrict__ s0, u16* __restrict__ d0,
                            const float* __restrict__ s1, u16* __restrict__ d1,
                            const float* __restrict__ s2, u16* __restrict__ d2) {
    const float* __restrict__ s; u16* __restrict__ d;
    switch (blockIdx.y) {
        case 0: s = s0; d = d0; break;
        case 1: s = s1; d = d1; break;
        default: s = s2; d = d2; break;
    }
    size_t i = (size_t)blockIdx.x * 256 + threadIdx.x;   // u16x8-group index
    f32x4 a = ((const f32x4*)s)[i * 2];
    f32x4 b = ((const f32x4*)s)[i * 2 + 1];
    u16x8 o;
#pragma unroll
    for (int j = 0; j < 4; j++) { o[j] = f2bf(a[j]); o[4 + j] = f2bf(b[j]); }
    ((u16x8*)d)[i] = o;
}

// ------- Router: scores, top-2, softmax, counts; also emits xb = bf16(x) -------
__global__ void router_kernel(const float* __restrict__ x, const float* __restrict__ wr,
                              int* cnt, int* rt_e, float* rt_p, u16* __restrict__ xb) {
    int wave = threadIdx.x >> 6, lane = threadIdx.x & 63;
    int t = blockIdx.x * 4 + wave;
    float xv[32];
#pragma unroll
    for (int i = 0; i < 32; i++) xv[i] = x[(size_t)t * DIM + i * 64 + lane];
#pragma unroll
    for (int i = 0; i < 32; i++) xb[(size_t)t * DIM + i * 64 + lane] = f2bf(xv[i]);
    float s[NEXP];
#pragma unroll
    for (int e = 0; e < NEXP; e++) {
        float acc = 0.f;
#pragma unroll
        for (int i = 0; i < 32; i++) acc += xv[i] * wr[(size_t)e * DIM + i * 64 + lane];
        for (int off = 32; off; off >>= 1) acc += __shfl_xor(acc, off);
        s[e] = acc;
    }
    if (lane == 0) {
        int bi = 0; float bv = s[0];
        for (int e = 1; e < NEXP; e++) if (s[e] > bv) { bv = s[e]; bi = e; }
        float sv = -1e30f; int si = 0;
        for (int e = 0; e < NEXP; e++) { if (e == bi) continue; if (s[e] > sv) { sv = s[e]; si = e; } }
        float p0 = 1.f / (1.f + __expf(sv - bv));
        float p1 = 1.f - p0;
        rt_e[t * 2 + 0] = bi; rt_e[t * 2 + 1] = si;
        rt_p[t * 2 + 0] = p0; rt_p[t * 2 + 1] = p1;
        atomicAdd(&cnt[bi * 2 + 0], 1);
        atomicAdd(&cnt[si * 2 + 1], 1);
    }
}

// ---- Fused scan + assign: one block. Wave 0 scans; all waves then assign rows. ----
__global__ void scanassign_kernel(const int* cnt, const int* rt_e, const float* rt_p,
                                  int* base_g, int* tile_g, int* tile_m0, int* ntiles,
                                  int* rowtok, float* rowprob) {
    __shared__ int s_base[NGRP];
    __shared__ int s_pos[NGRP];
    int tid = threadIdx.x;
    if (tid < NGRP) s_pos[tid] = 0;
    if (tid < 64) {
        int lane = tid;
        int c = (lane < NGRP) ? cnt[lane] : 0;
        int nt_g = (c + 127) >> 7;
        int pre = 0, tpre = 0;
        for (int i = 0; i < NGRP; i++) {
            int ci = __shfl(c, i), ti = __shfl(nt_g, i);
            if (i < lane) { pre += ci; tpre += ti; }
        }
        if (lane < NGRP) {
            s_base[lane] = pre; base_g[lane] = pre;
            for (int j = 0; j < nt_g; j++) { tile_g[tpre + j] = lane; tile_m0[tpre + j] = j * 128; }
            if (lane == NGRP - 1) *ntiles = tpre + nt_g;
        }
    }
    __syncthreads();
    for (int t = tid; t < T_TOK; t += 256) {
#pragma unroll
        for (int k = 0; k < 2; k++) {
            int g = rt_e[t * 2 + k] * 2 + k;
            int pos = atomicAdd(&s_pos[g], 1);
            int row = s_base[g] + pos;
            rowtok[row] = t;
            rowprob[row] = rt_p[t * 2 + k];
        }
    }
}

// ---- Gate/Up GEMM + SiLU: m97-cell geometry ----
// 128x128 block (4 waves of 64x64, acc 4x4 = 16 MFMA per iter fed by 8 ds_read),
// BK=32, LDS 2x(8+8)=32 KB, single-barrier T3 loop:
// { stage(next -> buf^1); ds_read+MFMA(buf); __syncthreads(); flip }.
// Swizzle (r6-verified): store chunk c at c ^ ((row>>1)&3); read chunk
// quad ^ ((l16>>1)&3) -- fragment reads 2-way bank-aliased = free.
__launch_bounds__(256)
__global__ void gateup_kernel(const u16* __restrict__ xb, const u16* __restrict__ wgb,
                              const u16* __restrict__ wub,
                              const int* cnt, const int* base, const int* tile_g,
                              const int* tile_m0, const int* ntiles,
                              const int* rowtok, const float* rowprob,
                              u16* __restrict__ hidden) {
    int tile = blockIdx.x;
    if (tile >= *ntiles) return;
    int g = tile_g[tile], m0 = tile_m0[tile];
    int e = g >> 1;
    int f0 = blockIdx.y * 64;   // 64 f-values -> 128 B-rows (gate|up interleaved)
    int cg = cnt[g], bg_ = base[g];

    __shared__ u16 As[2][128 * BK];   // 2 x 8 KB
    __shared__ u16 Bs[2][128 * BK];   // 2 x 8 KB
    __shared__ int   tks[128];
    __shared__ float ps[128];

    int tid = threadIdx.x;
    if (tid < 128) {
        int valid = (m0 + tid) < cg;
        tks[tid] = valid ? rowtok[bg_ + m0 + tid] : 0;
        ps[tid]  = valid ? rowprob[bg_ + m0 + tid] : 0.f;
    }
    __syncthreads();

    int wave = tid >> 6, lane = tid & 63;
    int quad = lane >> 4, l16 = lane & 15;
    int wr = wave >> 1, wc = wave & 1;

    // staging: gload16 group = 16 rows x 4 chunks of 16B (row = 64B)
    int r4  = lane >> 2;                                 // row in group
    int csw = ((lane & 3) ^ ((r4 >> 1) & 3)) * 8;        // inverse-swizzled src chunk

    // A: wave stages rows [wave*32, +32) in 2 groups of 16
    const u16* gA[2]; int lA[2];
#pragma unroll
    for (int gi = 0; gi < 2; gi++) {
        int row = wave * 32 + gi * 16 + r4;
        gA[gi] = xb + (size_t)tks[row] * DIM + csw;
        lA[gi] = (wave * 32 + gi * 16) * BK;
    }
    // B LDS rows n in [0,128): type=(n>>4)&1 (0=gate,1=up), f = f0+(n>>5)*16+(n&15)
    // wave stages rows [wave*32,+32): gi=0 -> gate, gi=1 -> up, f = f0 + wave*16 + r4
    const u16* gB[2]; int lB[2];
#pragma unroll
    for (int gi = 0; gi < 2; gi++) {
        const u16* bsrc = gi ? wub : wgb;
        gB[gi] = bsrc + ((size_t)e * FF + f0 + wave * 16 + r4) * DIM + csw;
        lB[gi] = (wave * 32 + gi * 16) * BK;
    }

    // ds-read offsets (loop-invariant)
    int swz = (quad ^ ((l16 >> 1) & 3)) * 8;
    int aoff[4], boff[4];
#pragma unroll
    for (int mi = 0; mi < 4; mi++) aoff[mi] = (wr * 64 + mi * 16 + l16) * BK + swz;
#pragma unroll
    for (int ni = 0; ni < 4; ni++) boff[ni] = (wc * 64 + ni * 16 + l16) * BK + swz;

    f32x4 acc[4][4] = {};

    // prologue: stage buffer 0
#pragma unroll
    for (int gi = 0; gi < 2; gi++) gload16(gA[gi], &As[0][0] + lA[gi]);
#pragma unroll
    for (int gi = 0; gi < 2; gi++) gload16(gB[gi], &Bs[0][0] + lB[gi]);
    __syncthreads();

    int cur = 0;
    for (int kt = 0; kt < DIM / BK; kt++) {
        int kk = (kt + 1) * BK;
        if (kk < DIM) {
#pragma unroll
            for (int gi = 0; gi < 2; gi++) gload16(gA[gi] + kk, &As[cur ^ 1][0] + lA[gi]);
#pragma unroll
            for (int gi = 0; gi < 2; gi++) gload16(gB[gi] + kk, &Bs[cur ^ 1][0] + lB[gi]);
        }
        bf16x8 a[4], b[4];
#pragma unroll
        for (int mi = 0; mi < 4; mi++) a[mi] = *(const bf16x8*)&As[cur][aoff[mi]];
#pragma unroll
        for (int ni = 0; ni < 4; ni++) b[ni] = *(const bf16x8*)&Bs[cur][boff[ni]];
#pragma unroll
        for (int mi = 0; mi < 4; mi++)
#pragma unroll
            for (int ni = 0; ni < 4; ni++)
                acc[mi][ni] = __builtin_amdgcn_mfma_f32_16x16x32_bf16(a[mi], b[ni], acc[mi][ni], 0, 0, 0);
        __syncthreads();   // drains lgkm (reads of buf[cur]) AND vmcnt (next stage)
        cur ^= 1;
    }

    // epilogue: acc[mi][ni]: ni even=gate, odd=up; f = f0 + wc*32 + (ni>>1)*16 + l16
#pragma unroll
    for (int mi = 0; mi < 4; mi++) {
#pragma unroll
        for (int r = 0; r < 4; r++) {
            int m = wr * 64 + mi * 16 + quad * 4 + r;
            if (m0 + m < cg) {
                float p = ps[m];
                float g0 = acc[mi][0][r], u0 = acc[mi][1][r];
                float g1 = acc[mi][2][r], u1 = acc[mi][3][r];
                size_t rowo = (size_t)(bg_ + m0 + m) * FF + f0 + wc * 32 + l16;
                hidden[rowo]      = f2bf((g0 / (1.f + __expf(-g0))) * u0 * p);
                hidden[rowo + 16] = f2bf((g1 / (1.f + __expf(-g1))) * u1 * p);
            }
        }
    }
}

// ---- Down GEMM: m97-cell, 128 rows x 128 d, BK=32, single-barrier loop ----
// Epilogue: f32 atomicAdd straight into out (replaces bf16 scatter + combine pass).
__launch_bounds__(256)
__global__ void down_kernel(const u16* __restrict__ hid, const u16* __restrict__ wdb,
                            const int* cnt, const int* base, const int* tile_g,
                            const int* tile_m0, const int* ntiles, const int* rowtok,
                            float* __restrict__ out) {
    int tile = blockIdx.x;
    if (tile >= *ntiles) return;
    int g = tile_g[tile], m0 = tile_m0[tile];
    int e = g >> 1;
    int d0 = blockIdx.y * 128;
    int cg = cnt[g], bg_ = base[g];

    __shared__ u16 As[2][128 * BK];
    __shared__ u16 Bs[2][128 * BK];
    __shared__ int tks[128];

    int tid = threadIdx.x;
    if (tid < 128) tks[tid] = ((m0 + tid) < cg) ? rowtok[bg_ + m0 + tid] : 0;
    __syncthreads();

    int wave = tid >> 6, lane = tid & 63;
    int quad = lane >> 4, l16 = lane & 15;
    int wr = wave >> 1, wc = wave & 1;

    int r4  = lane >> 2;
    int csw = ((lane & 3) ^ ((r4 >> 1) & 3)) * 8;

    const u16* gA[2]; int lA[2];
#pragma unroll
    for (int gi = 0; gi < 2; gi++) {
        int row = wave * 32 + gi * 16 + r4;
        gA[gi] = hid + (size_t)(bg_ + m0 + row) * FF + csw;
        lA[gi] = (wave * 32 + gi * 16) * BK;
    }
    // B LDS row n in [0,128): d = d0 + n; wave stages rows [wave*32,+32)
    const u16* gB[2]; int lB[2];
#pragma unroll
    for (int gi = 0; gi < 2; gi++) {
        int n = wave * 32 + gi * 16 + r4;
        gB[gi] = wdb + ((size_t)e * DIM + d0 + n) * FF + csw;
        lB[gi] = (wave * 32 + gi * 16) * BK;
    }

    int swz = (quad ^ ((l16 >> 1) & 3)) * 8;
    int aoff[4], boff[4];
#pragma unroll
    for (int mi = 0; mi < 4; mi++) aoff[mi] = (wr * 64 + mi * 16 + l16) * BK + swz;
#pragma unroll
    for (int ni = 0; ni < 4; ni++) boff[ni] = (wc * 64 + ni * 16 + l16) * BK + swz;

    f32x4 acc[4][4] = {};

#pragma unroll
    for (int gi = 0; gi < 2; gi++) gload16(gA[gi], &As[0][0] + lA[gi]);
#pragma unroll
    for (int gi = 0; gi < 2; gi++) gload16(gB[gi], &Bs[0][0] + lB[gi]);
    __syncthreads();

    int cur = 0;
    for (int kt = 0; kt < FF / BK; kt++) {
        int kk = (kt + 1) * BK;
        if (kk < FF) {
#pragma unroll
            for (int gi = 0; gi < 2; gi++) gload16(gA[gi] + kk, &As[cur ^ 1][0] + lA[gi]);
#pragma unroll
            for (int gi = 0; gi < 2; gi++) gload16(gB[gi] + kk, &Bs[cur ^ 1][0] + lB[gi]);
        }
        bf16x8 a[4], b[4];
#pragma unroll
        for (int mi = 0; mi < 4; mi++) a[mi] = *(const bf16x8*)&As[cur][aoff[mi]];
#pragma unroll
        for (int ni = 0; ni < 4; ni++) b[ni] = *(const bf16x8*)&Bs[cur][boff[ni]];
#pragma unroll
        for (int mi = 0; mi < 4; mi++)
#pragma unroll
            for (int ni = 0; ni < 4; ni++)
                acc[mi][ni] = __builtin_amdgcn_mfma_f32_16x16x32_bf16(a[mi], b[ni], acc[mi][ni], 0, 0, 0);
        __syncthreads();
        cur ^= 1;
    }

#pragma unroll
    for (int mi = 0; mi < 4; mi++) {
#pragma unroll
        for (int ni = 0; ni < 4; ni++) {
            int d = d0 + wc * 64 + ni * 16 + l16;
#pragma unroll
            for (int r = 0; r < 4; r++) {
                int m = wr * 64 + mi * 16 + quad * 4 + r;
                if (m0 + m < cg) {
                    atomicAdd(&out[(size_t)tks[m] * DIM + d], acc[mi][ni][r]);
                }
            }
        }
    }
}

extern "C" void kernel_launch(void* const* d_in, const int* in_sizes, int n_in,
                              void* d_out, int out_size, void* d_ws, size_t ws_size,
                              hipStream_t stream) {
    const float* x  = (const float*)d_in[0];
    const float* wr = (const float*)d_in[1];
    const float* wg = (const float*)d_in[2];
    const float* wu = (const float*)d_in[3];
    const float* wd = (const float*)d_in[4];
    float* out = (float*)d_out;

    char* W = (char*)d_ws;
    int*   cnt     = (int*)(W + 0);
    int*   base    = (int*)(W + 128);
    int*   ntiles  = (int*)(W + 192);
    int*   tile_g  = (int*)(W + 256);           // <=48
    int*   tile_m0 = (int*)(W + 512);           // <=48
    int*   rt_e    = (int*)(W + 1024);          // 4096 ints
    float* rt_p    = (float*)(W + 20480);
    int*   rowtok  = (int*)(W + 40960);
    float* rowprob = (float*)(W + 61440);
    u16*   hidden  = (u16*)(W + 81920);         // (4096+128) x 768 bf16 ~ 6.49 MB
    u16*   xb      = (u16*)(W + ((size_t)8  << 20));   // 8.39 MB
    u16*   wgb     = (u16*)(W + ((size_t)17 << 20));   // 25.2 MB
    u16*   wub     = (u16*)(W + ((size_t)43 << 20));   // 25.2 MB
    u16*   wdb     = (u16*)(W + ((size_t)69 << 20));   // 25.2 MB  (end ~94.4 MB)

    hipMemsetAsync(W, 0, 256, stream);                                  // cnt, base, ntiles
    hipMemsetAsync(out, 0, (size_t)T_TOK * DIM * sizeof(float), stream); // atomic target

    // NW8 = NEXP*FF*DIM/8 = 1,572,864 = 6144 * 256 exactly
    cvt3_kernel<<<dim3(6144, 3), 256, 0, stream>>>(wg, wgb, wu, wub, wd, wdb);

    router_kernel<<<T_TOK / 4, 256, 0, stream>>>(x, wr, cnt, rt_e, rt_p, xb);
    scanassign_kernel<<<1, 256, 0, stream>>>(cnt, rt_e, rt_p, base, tile_g, tile_m0,
                                             ntiles, rowtok, rowprob);

    gateup_kernel<<<dim3(48, 12), 256, 0, stream>>>(xb, wgb, wub, cnt, base, tile_g, tile_m0,
                                                    ntiles, rowtok, rowprob, hidden);
    down_kernel<<<dim3(48, 16), 256, 0, stream>>>(hidden, wdb, cnt, base, tile_g, tile_m0,
                                                  ntiles, rowtok, out);
}